// Round 5
// baseline (97.648 us; speedup 1.0000x reference)
//
#include <hip/hip_runtime.h>

// ColorReducer: per pixel argmin_k ||p - palette[k]||^2, output palette color,
// planar (B,3,H,W) layout.
//
// CORRECTNESS CONTRACT (verified R4, absmax=0.0): ref=np fp32,
//   dot = fma(b,cb, fma(g,cg, rn(r*cr)))        ascending scalar FMA chain
//   pp  = ((r*r+g*g)+b*b), cc = ((cr*cr+cg*cg)+cb*cb)   fwd, no FMA
//   d   = (pp - 2*dot) + cc   left-to-right; 2*dot exact
//   argmin first-index strict <
// All reproduced with __f*_rn / explicit elementwise fma; packed f32 (v_pk_*)
// is IEEE-identical per half so pixel-pairing preserves bit-exactness.
//
// R5 perf change: NO LDS in the hot loop. Palette coefficients are
// wave-uniform -> compiler s_loads them into SGPRs (constant cache), VALU ops
// take the SGPR operand directly. Pixel pairs packed as float2 so the 6-op
// arithmetic chain maps to v_pk_fma_f32/v_pk_add_f32. LDS retained only for
// the final palette gather.

typedef float f2 __attribute__((ext_vector_type(2)));

constexpr int HW   = 512 * 512;   // pixels per plane (2^18)
constexpr int NCOL = 64;

__global__ __launch_bounds__(256)
void color_reduce_kernel(const float* __restrict__ x,
                         const float* __restrict__ pal,
                         float* __restrict__ out,
                         int npix4) {
  __shared__ float4 praw[NCOL];   // (r,g,b,0) for the final gather only
  const int tid = threadIdx.x;
  if (tid < NCOL) {
    praw[tid] = make_float4(pal[tid * 3 + 0], pal[tid * 3 + 1],
                            pal[tid * 3 + 2], 0.f);
  }
  __syncthreads();

  const int i4 = blockIdx.x * blockDim.x + tid;   // group of 4 consecutive pixels
  if (i4 >= npix4) return;
  const int pix = i4 << 2;
  const int bi  = pix >> 18;        // / HW
  const int j   = pix & (HW - 1);   // % HW
  const size_t base = (size_t)bi * (3 * HW) + j;

  const float4 R = *(const float4*)(x + base);
  const float4 G = *(const float4*)(x + base + HW);
  const float4 B = *(const float4*)(x + base + 2 * HW);

  const float rr[4] = {R.x, R.y, R.z, R.w};
  const float gg[4] = {G.x, G.y, G.z, G.w};
  const float bv[4] = {B.x, B.y, B.z, B.w};
  float pp[4];
#pragma unroll
  for (int p = 0; p < 4; ++p)
    pp[p] = __fadd_rn(__fadd_rn(__fmul_rn(rr[p], rr[p]), __fmul_rn(gg[p], gg[p])),
                      __fmul_rn(bv[p], bv[p]));

  const f2 r01 = {R.x, R.y}, r23 = {R.z, R.w};
  const f2 g01 = {G.x, G.y}, g23 = {G.z, G.w};
  const f2 b01 = {B.x, B.y}, b23 = {B.z, B.w};
  const f2 pp01 = {pp[0], pp[1]}, pp23 = {pp[2], pp[3]};

  float m0 = 3.4e38f, m1 = 3.4e38f, m2 = 3.4e38f, m3 = 3.4e38f;
  int id0 = 0, id1 = 0, id2 = 0, id3 = 0;

#pragma unroll 8
  for (int k = 0; k < NCOL; ++k) {
    // Uniform reads -> SGPRs via constant cache; no LDS, no per-lane VMEM.
    const float cr = pal[k * 3 + 0];
    const float cg = pal[k * 3 + 1];
    const float cb = pal[k * 3 + 2];
    const float cc = __fadd_rn(__fadd_rn(__fmul_rn(cr, cr), __fmul_rn(cg, cg)),
                               __fmul_rn(cb, cb));
    const f2 crv = {cr, cr}, cgv = {cg, cg}, cbv = {cb, cb}, ccv = {cc, cc};

    // Exact numpy chain, packed over pixel pairs (per-half IEEE rn).
    f2 dot01 = __builtin_elementwise_fma(
        b01, cbv, __builtin_elementwise_fma(g01, cgv, r01 * crv));
    f2 dot23 = __builtin_elementwise_fma(
        b23, cbv, __builtin_elementwise_fma(g23, cgv, r23 * crv));
    const f2 e01 = (pp01 - (dot01 + dot01)) + ccv;   // no muls -> no contraction
    const f2 e23 = (pp23 - (dot23 + dot23)) + ccv;

    bool lt;
    lt = e01.x < m0; m0 = lt ? e01.x : m0; id0 = lt ? k : id0;
    lt = e01.y < m1; m1 = lt ? e01.y : m1; id1 = lt ? k : id1;
    lt = e23.x < m2; m2 = lt ? e23.x : m2; id2 = lt ? k : id2;
    lt = e23.y < m3; m3 = lt ? e23.y : m3; id3 = lt ? k : id3;
  }

  const float4 c0 = praw[id0], c1 = praw[id1], c2 = praw[id2], c3 = praw[id3];
  *(float4*)(out + base)          = make_float4(c0.x, c1.x, c2.x, c3.x);
  *(float4*)(out + base + HW)     = make_float4(c0.y, c1.y, c2.y, c3.y);
  *(float4*)(out + base + 2 * HW) = make_float4(c0.z, c1.z, c2.z, c3.z);
}

extern "C" void kernel_launch(void* const* d_in, const int* in_sizes, int n_in,
                              void* d_out, int out_size, void* d_ws, size_t ws_size,
                              hipStream_t stream) {
  const float* x   = (const float*)d_in[0];
  const float* pal = (const float*)d_in[1];
  float* out = (float*)d_out;

  const int npix  = in_sizes[0] / 3;   // B*H*W = 2,097,152
  const int npix4 = npix / 4;          // 524,288 threads -> 8192 waves, 8/SIMD
  const int block = 256;
  const int grid  = (npix4 + block - 1) / block;
  hipLaunchKernelGGL(color_reduce_kernel, dim3(grid), dim3(block), 0, stream,
                     x, pal, out, npix4);
}

// Round 6
// 97.520 us; speedup vs baseline: 1.0013x; 1.0013x over previous
//
#include <hip/hip_runtime.h>

// ColorReducer: per pixel argmin_k ||p - palette[k]||^2, output palette color,
// planar (B,3,H,W) layout.
//
// CORRECTNESS CONTRACT (verified R4/R5, absmax=0.0): ref=np fp32,
//   dot = fma(b,cb, fma(g,cg, rn(r*cr)))        ascending scalar FMA chain
//   pp  = ((r*r+g*g)+b*b), cc = ((cr*cr+cg*cg)+cb*cb)   fwd, no FMA
//   d   = (pp - 2*dot) + cc   left-to-right; 2*dot exact
//   argmin first-index strict <
// Packed f32 (v_pk_*) is IEEE-identical per half, so pixel-pairing preserves
// bit-exactness. DO NOT change the arithmetic op sequence.
//
// R6 perf change: pre-splatted coefficient table in d_ws, written by a tiny
// 64-thread kernel each call (ws is re-poisoned before every timed launch;
// same-stream ordering makes this graph-safe). Hot loop reads coefs as
// UNIFORM f2 loads -> s_load_dwordx2 into SGPR pairs; each v_pk_* op takes
// the SGPR pair directly (1 scalar operand/instr is legal). This removes the
// per-k cc recompute (3 VALU) and the {c,c} splat movs (~8 VALU) from the
// hot loop: 24 VALU instr per thread per color (12 pk arith + 12 select).

typedef float f2 __attribute__((ext_vector_type(2)));

constexpr int HW   = 512 * 512;   // pixels per plane (2^18)
constexpr int NCOL = 64;

__global__ __launch_bounds__(64)
void coef_kernel(const float* __restrict__ pal, f2* __restrict__ coef) {
  const int k = threadIdx.x;
  if (k < NCOL) {
    const float cr = pal[k * 3 + 0];
    const float cg = pal[k * 3 + 1];
    const float cb = pal[k * 3 + 2];
    // cc: forward sequential, no FMA (contract)
    const float cc = __fadd_rn(__fadd_rn(__fmul_rn(cr, cr), __fmul_rn(cg, cg)),
                               __fmul_rn(cb, cb));
    coef[k * 4 + 0] = (f2){cr, cr};
    coef[k * 4 + 1] = (f2){cg, cg};
    coef[k * 4 + 2] = (f2){cb, cb};
    coef[k * 4 + 3] = (f2){cc, cc};
  }
}

__global__ __launch_bounds__(256)
void color_reduce_kernel(const float* __restrict__ x,
                         const float* __restrict__ pal,
                         const f2* __restrict__ coef,
                         float* __restrict__ out,
                         int npix4) {
  __shared__ float4 praw[NCOL];   // (r,g,b,0) for the final gather only
  const int tid = threadIdx.x;
  if (tid < NCOL) {
    praw[tid] = make_float4(pal[tid * 3 + 0], pal[tid * 3 + 1],
                            pal[tid * 3 + 2], 0.f);
  }
  __syncthreads();

  const int i4 = blockIdx.x * blockDim.x + tid;   // group of 4 consecutive pixels
  if (i4 >= npix4) return;
  const int pix = i4 << 2;
  const int bi  = pix >> 18;        // / HW
  const int j   = pix & (HW - 1);   // % HW
  const size_t base = (size_t)bi * (3 * HW) + j;

  const float4 R = *(const float4*)(x + base);
  const float4 G = *(const float4*)(x + base + HW);
  const float4 B = *(const float4*)(x + base + 2 * HW);

  // pp: forward sequential, no FMA (contract)
  float pp[4];
  const float rr[4] = {R.x, R.y, R.z, R.w};
  const float gg[4] = {G.x, G.y, G.z, G.w};
  const float bv[4] = {B.x, B.y, B.z, B.w};
#pragma unroll
  for (int p = 0; p < 4; ++p)
    pp[p] = __fadd_rn(__fadd_rn(__fmul_rn(rr[p], rr[p]), __fmul_rn(gg[p], gg[p])),
                      __fmul_rn(bv[p], bv[p]));

  const f2 r01 = {R.x, R.y}, r23 = {R.z, R.w};
  const f2 g01 = {G.x, G.y}, g23 = {G.z, G.w};
  const f2 b01 = {B.x, B.y}, b23 = {B.z, B.w};
  const f2 pp01 = {pp[0], pp[1]}, pp23 = {pp[2], pp[3]};

  float m0 = 3.4e38f, m1 = 3.4e38f, m2 = 3.4e38f, m3 = 3.4e38f;
  int id0 = 0, id1 = 0, id2 = 0, id3 = 0;

#pragma unroll 8
  for (int k = 0; k < NCOL; ++k) {
    // Uniform loads -> s_load_dwordx2 pairs (SGPR); pk ops consume directly.
    const f2 crv = coef[k * 4 + 0];
    const f2 cgv = coef[k * 4 + 1];
    const f2 cbv = coef[k * 4 + 2];
    const f2 ccv = coef[k * 4 + 3];

    // Exact numpy chain, packed over pixel pairs (per-half IEEE rn).
    f2 dot01 = __builtin_elementwise_fma(
        b01, cbv, __builtin_elementwise_fma(g01, cgv, r01 * crv));
    f2 dot23 = __builtin_elementwise_fma(
        b23, cbv, __builtin_elementwise_fma(g23, cgv, r23 * crv));
    const f2 e01 = (pp01 - (dot01 + dot01)) + ccv;   // no muls -> no contraction
    const f2 e23 = (pp23 - (dot23 + dot23)) + ccv;

    bool lt;
    lt = e01.x < m0; m0 = lt ? e01.x : m0; id0 = lt ? k : id0;
    lt = e01.y < m1; m1 = lt ? e01.y : m1; id1 = lt ? k : id1;
    lt = e23.x < m2; m2 = lt ? e23.x : m2; id2 = lt ? k : id2;
    lt = e23.y < m3; m3 = lt ? e23.y : m3; id3 = lt ? k : id3;
  }

  const float4 c0 = praw[id0], c1 = praw[id1], c2 = praw[id2], c3 = praw[id3];
  *(float4*)(out + base)          = make_float4(c0.x, c1.x, c2.x, c3.x);
  *(float4*)(out + base + HW)     = make_float4(c0.y, c1.y, c2.y, c3.y);
  *(float4*)(out + base + 2 * HW) = make_float4(c0.z, c1.z, c2.z, c3.z);
}

extern "C" void kernel_launch(void* const* d_in, const int* in_sizes, int n_in,
                              void* d_out, int out_size, void* d_ws, size_t ws_size,
                              hipStream_t stream) {
  const float* x   = (const float*)d_in[0];
  const float* pal = (const float*)d_in[1];
  float* out = (float*)d_out;
  f2* coef = (f2*)d_ws;   // 64 colors x 4 splat pairs = 2 KiB

  hipLaunchKernelGGL(coef_kernel, dim3(1), dim3(64), 0, stream, pal, coef);

  const int npix  = in_sizes[0] / 3;   // B*H*W = 2,097,152
  const int npix4 = npix / 4;          // 524,288 threads -> 8192 waves, 8/SIMD
  const int block = 256;
  const int grid  = (npix4 + block - 1) / block;
  hipLaunchKernelGGL(color_reduce_kernel, dim3(grid), dim3(block), 0, stream,
                     x, pal, coef, out, npix4);
}